// Round 10
// baseline (313.958 us; speedup 1.0000x reference)
//
#include <hip/hip_runtime.h>
#include <hip/hip_bf16.h>

#define N_NODES 100000
#define N_EDGES 1600000
#define N_PAD   100096          // N rounded up to 128
#define BSHIFT  7               // 128 nodes per bucket
#define NBUCKET 782             // ceil(N_NODES / 128)
#define BCAP    3072            // capacity per bucket (avg fill ~2046, sigma ~45)
#define EPB     2048            // edges per scatter block -> 782 blocks (3/CU)

__device__ __forceinline__ unsigned short f32_to_bf16(float f) {
    unsigned int u = __float_as_uint(f);
    unsigned int r = (u + 0x7fffu + ((u >> 16) & 1u)) >> 16;
    return (unsigned short)r;
}
__device__ __forceinline__ float bf16_lo(unsigned int p) {   // low 16 bits
    return __uint_as_float(p << 16);
}
__device__ __forceinline__ float bf16_hi(unsigned int p) {   // high 16 bits
    return __uint_as_float(p & 0xffff0000u);
}

// ---------- scatter: per-block LDS hist -> bulk reserve -> packed writes ----
__global__ void __launch_bounds__(256) bucket_scatter_lds(
    const int* __restrict__ src, const int* __restrict__ dst,
    int* __restrict__ bcur, unsigned int* __restrict__ tmp, int n_edges) {
    __shared__ int lh[1024];     // histogram, then per-bucket write cursor
    int t = threadIdx.x;
    int e0 = blockIdx.x * EPB;
    int e1 = min(e0 + EPB, n_edges);
    for (int i = t; i < 1024; i += 256) lh[i] = 0;
    __syncthreads();
    for (int e = e0 + t; e < e1; e += 256)
        atomicAdd(&lh[dst[e] >> BSHIFT], 1);
    __syncthreads();
    for (int i = t; i < NBUCKET; i += 256) {
        int c = lh[i];
        lh[i] = (c > 0) ? atomicAdd(&bcur[i], c) : 0;
    }
    __syncthreads();
    for (int e = e0 + t; e < e1; e += 256) {
        int s = src[e], d = dst[e];
        int b = d >> BSHIFT;
        int p = atomicAdd(&lh[b], 1);
        if (p < BCAP)
            tmp[(size_t)b * BCAP + p] = ((unsigned)s << BSHIFT) | (unsigned)(d & 127);
    }
}

// ---------- per-bucket -> CSR in bucket-padded col space ------
__global__ void __launch_bounds__(256) bucket_to_csr(
    const unsigned int* __restrict__ tmp, const int* __restrict__ bcur,
    int* __restrict__ row_ptr, int* __restrict__ cnt,
    int* __restrict__ col, int n_nodes) {
    __shared__ int nh[128];
    __shared__ int npref[128];
    int b = blockIdx.x;
    int t = threadIdx.x;
    int m = min(bcur[b], BCAP);
    int cbase = b * BCAP;
    if (t < 128) nh[t] = 0;
    __syncthreads();
    const unsigned int* te = tmp + (size_t)b * BCAP;
    for (int i = t; i < m; i += 256) atomicAdd(&nh[te[i] & 127], 1);
    __syncthreads();
    if (t < 128) npref[t] = nh[t];
    __syncthreads();
    for (int off = 1; off < 128; off <<= 1) {
        int u = (t < 128 && t >= off) ? npref[t - off] : 0;
        __syncthreads();
        if (t < 128) npref[t] += u;
        __syncthreads();
    }
    if (t < 128) {
        int node = (b << BSHIFT) + t;
        int ex = npref[t] - nh[t];          // exclusive prefix
        if (node < n_nodes) { row_ptr[node] = cbase + ex; cnt[node] = nh[t]; }
        nh[t] = cbase + ex;                 // repurpose as placement cursor
    }
    __syncthreads();
    for (int i = t; i < m; i += 256) {
        unsigned int e = te[i];
        int pos = atomicAdd(&nh[e & 127], 1);
        col[pos] = (int)(e >> BSHIFT);
    }
}

// ---------- dense GEMM: Y[M,64] = X[M,64] @ W[64,64], Y stored bf16 row-major -
__global__ void __launch_bounds__(256) gemm_n64(const float4* __restrict__ X4,
                                                const float* __restrict__ W,
                                                unsigned short* __restrict__ Y, int M) {
    __shared__ float sx[64][65];
    __shared__ float sw[64 * 64];
    int t = threadIdx.x;
    int base = blockIdx.x * 64;
    for (int i = t; i < 64 * 16; i += 256) {
        int r = i >> 4, c4 = i & 15;
        int row = base + r;
        float4 v = make_float4(0.f, 0.f, 0.f, 0.f);
        if (row < M) v = X4[(size_t)row * 16 + c4];
        sx[r][c4 * 4 + 0] = v.x; sx[r][c4 * 4 + 1] = v.y;
        sx[r][c4 * 4 + 2] = v.z; sx[r][c4 * 4 + 3] = v.w;
    }
    float4* sw4 = (float4*)sw;
    const float4* W4 = (const float4*)W;
    for (int i = t; i < 64 * 16; i += 256) sw4[i] = W4[i];
    __syncthreads();

    int tm = t & 15;
    int tn = t >> 4;
    float acc[4][4] = {{0.f}};
    #pragma unroll 8
    for (int k = 0; k < 64; k++) {
        float4 b = sw4[k * 16 + tn];
        float a0 = sx[tm * 4 + 0][k], a1 = sx[tm * 4 + 1][k];
        float a2 = sx[tm * 4 + 2][k], a3 = sx[tm * 4 + 3][k];
        acc[0][0] = fmaf(a0, b.x, acc[0][0]); acc[0][1] = fmaf(a0, b.y, acc[0][1]);
        acc[0][2] = fmaf(a0, b.z, acc[0][2]); acc[0][3] = fmaf(a0, b.w, acc[0][3]);
        acc[1][0] = fmaf(a1, b.x, acc[1][0]); acc[1][1] = fmaf(a1, b.y, acc[1][1]);
        acc[1][2] = fmaf(a1, b.z, acc[1][2]); acc[1][3] = fmaf(a1, b.w, acc[1][3]);
        acc[2][0] = fmaf(a2, b.x, acc[2][0]); acc[2][1] = fmaf(a2, b.y, acc[2][1]);
        acc[2][2] = fmaf(a2, b.z, acc[2][2]); acc[2][3] = fmaf(a2, b.w, acc[2][3]);
        acc[3][0] = fmaf(a3, b.x, acc[3][0]); acc[3][1] = fmaf(a3, b.y, acc[3][1]);
        acc[3][2] = fmaf(a3, b.z, acc[3][2]); acc[3][3] = fmaf(a3, b.w, acc[3][3]);
    }
    #pragma unroll
    for (int i = 0; i < 4; i++) {
        int row = base + tm * 4 + i;
        if (row < M) {
            ushort4 p;
            p.x = f32_to_bf16(acc[i][0]); p.y = f32_to_bf16(acc[i][1]);
            p.z = f32_to_bf16(acc[i][2]); p.w = f32_to_bf16(acc[i][3]);
            *(ushort4*)&Y[(size_t)row * 64 + tn * 4] = p;
        }
    }
}

// ---------- gather1+GEMV: z2[n] = relu(mean_agg(y)[n] + b1) @ W2 ------------
// One wave per node. Edge loop is WAVE-UNIFORM trip count with predicated
// body (d is wave-uniform) — divergent-trip form (i=g; i<d; i+=8) serialized
// the col->Y4 load chains and cost 2.4x in round 9.
__global__ void __launch_bounds__(256) gather_gemv(
    const uint4* __restrict__ Y4, const int* __restrict__ row_ptr,
    const int* __restrict__ col, const int* __restrict__ cnt,
    const float* __restrict__ b1, const float* __restrict__ W2,
    unsigned short* __restrict__ z2, int n_nodes) {
    int n = blockIdx.x * 4 + (threadIdx.x >> 6);
    if (n >= n_nodes) return;
    int lane = threadIdx.x & 63;
    int g = lane >> 3;          // edge subgroup 0..7 (later: j-chunk 0..7)
    int c = lane & 7;           // 8-feature k-chunk 0..7
    int beg = row_ptr[n];
    int d = cnt[n];

    // W2 slice: rows 8c..8c+8, cols 4g..4g+4 (32 VGPRs, L1/L2-hit loads)
    float4 w2v[8];
    #pragma unroll
    for (int q = 0; q < 8; q++)
        w2v[q] = *(const float4*)&W2[(8 * c + q) * 32 + 4 * g];

    float acc[8] = {0.f, 0.f, 0.f, 0.f, 0.f, 0.f, 0.f, 0.f};
    for (int i = 0; i < d; i += 8) {        // uniform backedge, predicated body
        int idx = i + g;
        if (idx < d) {
            int s = col[beg + idx];
            uint4 v = Y4[(size_t)s * 8 + c];
            acc[0] += bf16_lo(v.x); acc[1] += bf16_hi(v.x);
            acc[2] += bf16_lo(v.y); acc[3] += bf16_hi(v.y);
            acc[4] += bf16_lo(v.z); acc[5] += bf16_hi(v.z);
            acc[6] += bf16_lo(v.w); acc[7] += bf16_hi(v.w);
        }
    }
    #pragma unroll
    for (int m = 8; m <= 32; m <<= 1) {
        #pragma unroll
        for (int q = 0; q < 8; q++) acc[q] += __shfl_xor(acc[q], m);
    }
    // bias + relu in registers (all lanes hold full sums for chunk c)
    float inv = 1.0f / fmaxf((float)d, 1.0f);
    const float4* b1_4 = (const float4*)b1;
    float4 ba = b1_4[c * 2], bb = b1_4[c * 2 + 1];
    float hq[8];
    hq[0] = fmaxf(fmaf(acc[0], inv, ba.x), 0.f);
    hq[1] = fmaxf(fmaf(acc[1], inv, ba.y), 0.f);
    hq[2] = fmaxf(fmaf(acc[2], inv, ba.z), 0.f);
    hq[3] = fmaxf(fmaf(acc[3], inv, ba.w), 0.f);
    hq[4] = fmaxf(fmaf(acc[4], inv, bb.x), 0.f);
    hq[5] = fmaxf(fmaf(acc[5], inv, bb.y), 0.f);
    hq[6] = fmaxf(fmaf(acc[6], inv, bb.z), 0.f);
    hq[7] = fmaxf(fmaf(acc[7], inv, bb.w), 0.f);
    // partial GEMV over this lane's k-chunk
    float z0 = 0.f, z1 = 0.f, z2v = 0.f, z3 = 0.f;
    #pragma unroll
    for (int q = 0; q < 8; q++) {
        z0 = fmaf(hq[q], w2v[q].x, z0);
        z1 = fmaf(hq[q], w2v[q].y, z1);
        z2v = fmaf(hq[q], w2v[q].z, z2v);
        z3 = fmaf(hq[q], w2v[q].w, z3);
    }
    // reduce partials across the 8 k-chunks (lane bits 0..2)
    #pragma unroll
    for (int m = 1; m <= 4; m <<= 1) {
        z0 += __shfl_xor(z0, m); z1 += __shfl_xor(z1, m);
        z2v += __shfl_xor(z2v, m); z3 += __shfl_xor(z3, m);
    }
    if (c == 0) {   // 8 lanes (g=0..7) write feats 4g..4g+4: 64B/node total
        ushort4 p;
        p.x = f32_to_bf16(z0); p.y = f32_to_bf16(z1);
        p.z = f32_to_bf16(z2v); p.w = f32_to_bf16(z3);
        *(ushort4*)&z2[(size_t)n * 32 + g * 4] = p;
    }
}

// ---------- gather2: out[n] = sigmoid(mean_f(relu(mean_agg(z2)[n]+b2))*Wd+bd) --
__global__ void __launch_bounds__(256) gather_final32(
    const uint4* __restrict__ Z4, const int* __restrict__ row_ptr,
    const int* __restrict__ col, const int* __restrict__ cnt,
    const float* __restrict__ b2, const float* __restrict__ Wd,
    const float* __restrict__ bd, float* __restrict__ out, int n_nodes) {
    int n = blockIdx.x * 4 + (threadIdx.x >> 6);
    if (n >= n_nodes) return;
    int lane = threadIdx.x & 63;
    int g = lane >> 2;          // edge subgroup 0..15
    int c = lane & 3;           // 8-feature chunk 0..3
    int beg = row_ptr[n];
    int d = cnt[n];

    float acc[8] = {0.f, 0.f, 0.f, 0.f, 0.f, 0.f, 0.f, 0.f};
    for (int i = 0; i < d; i += 16) {       // uniform backedge, predicated body
        int idx = i + g;
        if (idx < d) {
            int s = col[beg + idx];
            uint4 v = Z4[(size_t)s * 4 + c];
            acc[0] += bf16_lo(v.x); acc[1] += bf16_hi(v.x);
            acc[2] += bf16_lo(v.y); acc[3] += bf16_hi(v.y);
            acc[4] += bf16_lo(v.z); acc[5] += bf16_hi(v.z);
            acc[6] += bf16_lo(v.w); acc[7] += bf16_hi(v.w);
        }
    }
    #pragma unroll
    for (int m = 4; m <= 32; m <<= 1) {
        #pragma unroll
        for (int q = 0; q < 8; q++) acc[q] += __shfl_xor(acc[q], m);
    }
    float inv = 1.0f / fmaxf((float)d, 1.0f);
    const float4* b2_4 = (const float4*)b2;
    float4 ba = b2_4[c * 2], bb = b2_4[c * 2 + 1];
    float local = 0.f;
    local += fmaxf(fmaf(acc[0], inv, ba.x), 0.f);
    local += fmaxf(fmaf(acc[1], inv, ba.y), 0.f);
    local += fmaxf(fmaf(acc[2], inv, ba.z), 0.f);
    local += fmaxf(fmaf(acc[3], inv, ba.w), 0.f);
    local += fmaxf(fmaf(acc[4], inv, bb.x), 0.f);
    local += fmaxf(fmaf(acc[5], inv, bb.y), 0.f);
    local += fmaxf(fmaf(acc[6], inv, bb.z), 0.f);
    local += fmaxf(fmaf(acc[7], inv, bb.w), 0.f);
    local += __shfl_xor(local, 1);
    local += __shfl_xor(local, 2);
    if (lane == 0) {
        float z = fmaf(local * (1.0f / 32.0f), Wd[0], bd[0]);
        out[n] = 1.0f / (1.0f + __expf(-z));
    }
}

extern "C" void kernel_launch(void* const* d_in, const int* in_sizes, int n_in,
                              void* d_out, int out_size, void* d_ws, size_t ws_size,
                              hipStream_t stream) {
    const float* x    = (const float*)d_in[0];   // [N,64]
    const int*   esrc = (const int*)d_in[1];     // [E]
    const int*   edst = (const int*)d_in[2];     // [E]
    const float* W1   = (const float*)d_in[3];   // [64,64]
    const float* b1   = (const float*)d_in[4];   // [64]
    const float* W2   = (const float*)d_in[5];   // [64,32]
    const float* b2   = (const float*)d_in[6];   // [32]
    const float* Wd   = (const float*)d_in[7];   // [1,1]
    const float* bd   = (const float*)d_in[8];   // [1]
    float* out = (float*)d_out;                  // [N,1]

    // workspace (~39.3 MB):
    //   bcur[1024] row_ptr[N_PAD] cnt[N_PAD] col[NBUCKET*BCAP] (9.6MB)
    //   tmp uint[NBUCKET*BCAP] (9.6MB) | y bf16[N,64] (12.8MB) | z2 bf16[N,32] (6.4MB)
    int* bcur    = (int*)d_ws;
    int* row_ptr = bcur + 1024;
    int* cnt     = row_ptr + N_PAD;
    int* col     = cnt + N_PAD;
    unsigned int* tmp  = (unsigned int*)(col + (size_t)NBUCKET * BCAP);
    unsigned short* y  = (unsigned short*)(tmp + (size_t)NBUCKET * BCAP);
    unsigned short* z2 = y + (size_t)N_NODES * 64;   // separate: gather_gemv reads y, writes z2

    hipMemsetAsync((void*)bcur, 0, 1024 * sizeof(int), stream);

    // bucketed CSR build (packed 4B records: src<<7 | dst_local)
    bucket_scatter_lds<<<(N_EDGES + EPB - 1) / EPB, 256, 0, stream>>>(
        esrc, edst, bcur, tmp, N_EDGES);
    bucket_to_csr<<<NBUCKET, 256, 0, stream>>>(tmp, bcur, row_ptr, cnt, col, N_NODES);

    // y = x @ W1 (bf16 row-major)
    gemm_n64<<<(N_NODES + 63) / 64, 256, 0, stream>>>((const float4*)x, W1, y, N_NODES);
    // z2 = relu(mean_agg(y) + b1) @ W2  (fused; h never materialized)
    gather_gemv<<<(N_NODES + 3) / 4, 256, 0, stream>>>(
        (const uint4*)y, row_ptr, col, cnt, b1, W2, z2, N_NODES);
    // out = sigmoid(mean(relu(mean_agg(z2) + b2)) * Wd + bd)
    gather_final32<<<(N_NODES + 3) / 4, 256, 0, stream>>>(
        (const uint4*)z2, row_ptr, col, cnt, b2, Wd, bd, out, N_NODES);
}

// Round 11
// 306.146 us; speedup vs baseline: 1.0255x; 1.0255x over previous
//
#include <hip/hip_runtime.h>
#include <hip/hip_bf16.h>

#define N_NODES 100000
#define N_EDGES 1600000
#define N_PAD   100096          // N rounded up to 128
#define BSHIFT  7               // 128 nodes per bucket
#define NBUCKET 782             // ceil(N_NODES / 128)
#define BCAP    3072            // capacity per bucket (avg fill ~2046, sigma ~45)
#define EPB     2048            // edges per scatter block -> 782 blocks (3/CU)

__device__ __forceinline__ unsigned short f32_to_bf16(float f) {
    unsigned int u = __float_as_uint(f);
    unsigned int r = (u + 0x7fffu + ((u >> 16) & 1u)) >> 16;
    return (unsigned short)r;
}
__device__ __forceinline__ float bf16_lo(unsigned int p) {   // low 16 bits
    return __uint_as_float(p << 16);
}
__device__ __forceinline__ float bf16_hi(unsigned int p) {   // high 16 bits
    return __uint_as_float(p & 0xffff0000u);
}

// ---------- scatter: per-block LDS hist -> bulk reserve -> packed writes ----
__global__ void __launch_bounds__(256) bucket_scatter_lds(
    const int* __restrict__ src, const int* __restrict__ dst,
    int* __restrict__ bcur, unsigned int* __restrict__ tmp, int n_edges) {
    __shared__ int lh[1024];     // histogram, then per-bucket write cursor
    int t = threadIdx.x;
    int e0 = blockIdx.x * EPB;
    int e1 = min(e0 + EPB, n_edges);
    for (int i = t; i < 1024; i += 256) lh[i] = 0;
    __syncthreads();
    for (int e = e0 + t; e < e1; e += 256)
        atomicAdd(&lh[dst[e] >> BSHIFT], 1);
    __syncthreads();
    for (int i = t; i < NBUCKET; i += 256) {
        int c = lh[i];
        lh[i] = (c > 0) ? atomicAdd(&bcur[i], c) : 0;
    }
    __syncthreads();
    for (int e = e0 + t; e < e1; e += 256) {
        int s = src[e], d = dst[e];
        int b = d >> BSHIFT;
        int p = atomicAdd(&lh[b], 1);
        if (p < BCAP)
            tmp[(size_t)b * BCAP + p] = ((unsigned)s << BSHIFT) | (unsigned)(d & 127);
    }
}

// ---------- per-bucket -> CSR in bucket-padded col space ------
__global__ void __launch_bounds__(256) bucket_to_csr(
    const unsigned int* __restrict__ tmp, const int* __restrict__ bcur,
    int* __restrict__ row_ptr, int* __restrict__ cnt,
    int* __restrict__ col, int n_nodes) {
    __shared__ int nh[128];
    __shared__ int npref[128];
    int b = blockIdx.x;
    int t = threadIdx.x;
    int m = min(bcur[b], BCAP);
    int cbase = b * BCAP;
    if (t < 128) nh[t] = 0;
    __syncthreads();
    const unsigned int* te = tmp + (size_t)b * BCAP;
    for (int i = t; i < m; i += 256) atomicAdd(&nh[te[i] & 127], 1);
    __syncthreads();
    if (t < 128) npref[t] = nh[t];
    __syncthreads();
    for (int off = 1; off < 128; off <<= 1) {
        int u = (t < 128 && t >= off) ? npref[t - off] : 0;
        __syncthreads();
        if (t < 128) npref[t] += u;
        __syncthreads();
    }
    if (t < 128) {
        int node = (b << BSHIFT) + t;
        int ex = npref[t] - nh[t];          // exclusive prefix
        if (node < n_nodes) { row_ptr[node] = cbase + ex; cnt[node] = nh[t]; }
        nh[t] = cbase + ex;                 // repurpose as placement cursor
    }
    __syncthreads();
    for (int i = t; i < m; i += 256) {
        unsigned int e = te[i];
        int pos = atomicAdd(&nh[e & 127], 1);
        col[pos] = (int)(e >> BSHIFT);
    }
}

// ---------- dense GEMM: Y[M,64] = X[M,64] @ W[64,64], Y stored bf16 row-major -
__global__ void __launch_bounds__(256) gemm_n64(const float4* __restrict__ X4,
                                                const float* __restrict__ W,
                                                unsigned short* __restrict__ Y, int M) {
    __shared__ float sx[64][65];
    __shared__ float sw[64 * 64];
    int t = threadIdx.x;
    int base = blockIdx.x * 64;
    for (int i = t; i < 64 * 16; i += 256) {
        int r = i >> 4, c4 = i & 15;
        int row = base + r;
        float4 v = make_float4(0.f, 0.f, 0.f, 0.f);
        if (row < M) v = X4[(size_t)row * 16 + c4];
        sx[r][c4 * 4 + 0] = v.x; sx[r][c4 * 4 + 1] = v.y;
        sx[r][c4 * 4 + 2] = v.z; sx[r][c4 * 4 + 3] = v.w;
    }
    float4* sw4 = (float4*)sw;
    const float4* W4 = (const float4*)W;
    for (int i = t; i < 64 * 16; i += 256) sw4[i] = W4[i];
    __syncthreads();

    int tm = t & 15;
    int tn = t >> 4;
    float acc[4][4] = {{0.f}};
    #pragma unroll 8
    for (int k = 0; k < 64; k++) {
        float4 b = sw4[k * 16 + tn];
        float a0 = sx[tm * 4 + 0][k], a1 = sx[tm * 4 + 1][k];
        float a2 = sx[tm * 4 + 2][k], a3 = sx[tm * 4 + 3][k];
        acc[0][0] = fmaf(a0, b.x, acc[0][0]); acc[0][1] = fmaf(a0, b.y, acc[0][1]);
        acc[0][2] = fmaf(a0, b.z, acc[0][2]); acc[0][3] = fmaf(a0, b.w, acc[0][3]);
        acc[1][0] = fmaf(a1, b.x, acc[1][0]); acc[1][1] = fmaf(a1, b.y, acc[1][1]);
        acc[1][2] = fmaf(a1, b.z, acc[1][2]); acc[1][3] = fmaf(a1, b.w, acc[1][3]);
        acc[2][0] = fmaf(a2, b.x, acc[2][0]); acc[2][1] = fmaf(a2, b.y, acc[2][1]);
        acc[2][2] = fmaf(a2, b.z, acc[2][2]); acc[2][3] = fmaf(a2, b.w, acc[2][3]);
        acc[3][0] = fmaf(a3, b.x, acc[3][0]); acc[3][1] = fmaf(a3, b.y, acc[3][1]);
        acc[3][2] = fmaf(a3, b.z, acc[3][2]); acc[3][3] = fmaf(a3, b.w, acc[3][3]);
    }
    #pragma unroll
    for (int i = 0; i < 4; i++) {
        int row = base + tm * 4 + i;
        if (row < M) {
            ushort4 p;
            p.x = f32_to_bf16(acc[i][0]); p.y = f32_to_bf16(acc[i][1]);
            p.z = f32_to_bf16(acc[i][2]); p.w = f32_to_bf16(acc[i][3]);
            *(ushort4*)&Y[(size_t)row * 64 + tn * 4] = p;
        }
    }
}

// ---------- gather1+GEMV: z2[n] = relu(mean_agg(y)[n] + b1) @ W2 ------------
// One wave per node. Edge loop: manual x2 unroll, BRANCHLESS (clamped index +
// mask), single basic block -> two independent col->Y4 chains in flight.
// W2 slice loads are moved AFTER the loop behind a sched_barrier so the loop
// runs at round-7 register pressure (the preload held 32 VGPRs live across
// the loop in round 9/10 and killed load pipelining: 53 -> 125 us).
__global__ void __launch_bounds__(256) gather_gemv(
    const uint4* __restrict__ Y4, const int* __restrict__ row_ptr,
    const int* __restrict__ col, const int* __restrict__ cnt,
    const float* __restrict__ b1, const float* __restrict__ W2,
    unsigned short* __restrict__ z2, int n_nodes) {
    int n = blockIdx.x * 4 + (threadIdx.x >> 6);
    if (n >= n_nodes) return;
    int lane = threadIdx.x & 63;
    int g = lane >> 3;          // edge subgroup 0..7 (later: j-chunk 0..7)
    int c = lane & 7;           // 8-feature k-chunk 0..7
    int beg = row_ptr[n];
    int d = cnt[n];

    float acc[8] = {0.f, 0.f, 0.f, 0.f, 0.f, 0.f, 0.f, 0.f};
    for (int i = 0; i < d; i += 16) {
        int idx0 = i + g;
        int idx1 = i + g + 8;
        int ii0 = min(idx0, d - 1);         // safe clamp (loop implies d >= 1)
        int ii1 = min(idx1, d - 1);
        int s0 = col[beg + ii0];
        int s1 = col[beg + ii1];
        uint4 v0 = Y4[(size_t)s0 * 8 + c];
        uint4 v1 = Y4[(size_t)s1 * 8 + c];
        unsigned m0 = (idx0 < d) ? 0xffffffffu : 0u;
        unsigned m1 = (idx1 < d) ? 0xffffffffu : 0u;
        v0.x &= m0; v0.y &= m0; v0.z &= m0; v0.w &= m0;
        v1.x &= m1; v1.y &= m1; v1.z &= m1; v1.w &= m1;
        acc[0] += bf16_lo(v0.x); acc[1] += bf16_hi(v0.x);
        acc[2] += bf16_lo(v0.y); acc[3] += bf16_hi(v0.y);
        acc[4] += bf16_lo(v0.z); acc[5] += bf16_hi(v0.z);
        acc[6] += bf16_lo(v0.w); acc[7] += bf16_hi(v0.w);
        acc[0] += bf16_lo(v1.x); acc[1] += bf16_hi(v1.x);
        acc[2] += bf16_lo(v1.y); acc[3] += bf16_hi(v1.y);
        acc[4] += bf16_lo(v1.z); acc[5] += bf16_hi(v1.z);
        acc[6] += bf16_lo(v1.w); acc[7] += bf16_hi(v1.w);
    }
    __builtin_amdgcn_sched_barrier(0);      // keep w2v loads out of the loop

    // W2 slice: rows 8c..8c+8, cols 4g..4g+4 (loaded post-loop, L1/L2-hit)
    float4 w2v[8];
    #pragma unroll
    for (int q = 0; q < 8; q++)
        w2v[q] = *(const float4*)&W2[(8 * c + q) * 32 + 4 * g];

    #pragma unroll
    for (int m = 8; m <= 32; m <<= 1) {
        #pragma unroll
        for (int q = 0; q < 8; q++) acc[q] += __shfl_xor(acc[q], m);
    }
    // bias + relu in registers (all lanes hold full sums for chunk c)
    float inv = 1.0f / fmaxf((float)d, 1.0f);
    const float4* b1_4 = (const float4*)b1;
    float4 ba = b1_4[c * 2], bb = b1_4[c * 2 + 1];
    float hq[8];
    hq[0] = fmaxf(fmaf(acc[0], inv, ba.x), 0.f);
    hq[1] = fmaxf(fmaf(acc[1], inv, ba.y), 0.f);
    hq[2] = fmaxf(fmaf(acc[2], inv, ba.z), 0.f);
    hq[3] = fmaxf(fmaf(acc[3], inv, ba.w), 0.f);
    hq[4] = fmaxf(fmaf(acc[4], inv, bb.x), 0.f);
    hq[5] = fmaxf(fmaf(acc[5], inv, bb.y), 0.f);
    hq[6] = fmaxf(fmaf(acc[6], inv, bb.z), 0.f);
    hq[7] = fmaxf(fmaf(acc[7], inv, bb.w), 0.f);
    // partial GEMV over this lane's k-chunk
    float z0 = 0.f, z1 = 0.f, z2v = 0.f, z3 = 0.f;
    #pragma unroll
    for (int q = 0; q < 8; q++) {
        z0 = fmaf(hq[q], w2v[q].x, z0);
        z1 = fmaf(hq[q], w2v[q].y, z1);
        z2v = fmaf(hq[q], w2v[q].z, z2v);
        z3 = fmaf(hq[q], w2v[q].w, z3);
    }
    // reduce partials across the 8 k-chunks (lane bits 0..2)
    #pragma unroll
    for (int m = 1; m <= 4; m <<= 1) {
        z0 += __shfl_xor(z0, m); z1 += __shfl_xor(z1, m);
        z2v += __shfl_xor(z2v, m); z3 += __shfl_xor(z3, m);
    }
    if (c == 0) {   // 8 lanes (g=0..7) write feats 4g..4g+4: 64B/node total
        ushort4 p;
        p.x = f32_to_bf16(z0); p.y = f32_to_bf16(z1);
        p.z = f32_to_bf16(z2v); p.w = f32_to_bf16(z3);
        *(ushort4*)&z2[(size_t)n * 32 + g * 4] = p;
    }
}

// ---------- gather2: out[n] = sigmoid(mean_f(relu(mean_agg(z2)[n]+b2))*Wd+bd) --
__global__ void __launch_bounds__(256) gather_final32(
    const uint4* __restrict__ Z4, const int* __restrict__ row_ptr,
    const int* __restrict__ col, const int* __restrict__ cnt,
    const float* __restrict__ b2, const float* __restrict__ Wd,
    const float* __restrict__ bd, float* __restrict__ out, int n_nodes) {
    int n = blockIdx.x * 4 + (threadIdx.x >> 6);
    if (n >= n_nodes) return;
    int lane = threadIdx.x & 63;
    int g = lane >> 2;          // edge subgroup 0..15
    int c = lane & 3;           // 8-feature chunk 0..3
    int beg = row_ptr[n];
    int d = cnt[n];

    float acc[8] = {0.f, 0.f, 0.f, 0.f, 0.f, 0.f, 0.f, 0.f};
    for (int i = 0; i < d; i += 16) {       // uniform backedge, predicated body
        int idx = i + g;
        if (idx < d) {
            int s = col[beg + idx];
            uint4 v = Z4[(size_t)s * 4 + c];
            acc[0] += bf16_lo(v.x); acc[1] += bf16_hi(v.x);
            acc[2] += bf16_lo(v.y); acc[3] += bf16_hi(v.y);
            acc[4] += bf16_lo(v.z); acc[5] += bf16_hi(v.z);
            acc[6] += bf16_lo(v.w); acc[7] += bf16_hi(v.w);
        }
    }
    #pragma unroll
    for (int m = 4; m <= 32; m <<= 1) {
        #pragma unroll
        for (int q = 0; q < 8; q++) acc[q] += __shfl_xor(acc[q], m);
    }
    float inv = 1.0f / fmaxf((float)d, 1.0f);
    const float4* b2_4 = (const float4*)b2;
    float4 ba = b2_4[c * 2], bb = b2_4[c * 2 + 1];
    float local = 0.f;
    local += fmaxf(fmaf(acc[0], inv, ba.x), 0.f);
    local += fmaxf(fmaf(acc[1], inv, ba.y), 0.f);
    local += fmaxf(fmaf(acc[2], inv, ba.z), 0.f);
    local += fmaxf(fmaf(acc[3], inv, ba.w), 0.f);
    local += fmaxf(fmaf(acc[4], inv, bb.x), 0.f);
    local += fmaxf(fmaf(acc[5], inv, bb.y), 0.f);
    local += fmaxf(fmaf(acc[6], inv, bb.z), 0.f);
    local += fmaxf(fmaf(acc[7], inv, bb.w), 0.f);
    local += __shfl_xor(local, 1);
    local += __shfl_xor(local, 2);
    if (lane == 0) {
        float z = fmaf(local * (1.0f / 32.0f), Wd[0], bd[0]);
        out[n] = 1.0f / (1.0f + __expf(-z));
    }
}

extern "C" void kernel_launch(void* const* d_in, const int* in_sizes, int n_in,
                              void* d_out, int out_size, void* d_ws, size_t ws_size,
                              hipStream_t stream) {
    const float* x    = (const float*)d_in[0];   // [N,64]
    const int*   esrc = (const int*)d_in[1];     // [E]
    const int*   edst = (const int*)d_in[2];     // [E]
    const float* W1   = (const float*)d_in[3];   // [64,64]
    const float* b1   = (const float*)d_in[4];   // [64]
    const float* W2   = (const float*)d_in[5];   // [64,32]
    const float* b2   = (const float*)d_in[6];   // [32]
    const float* Wd   = (const float*)d_in[7];   // [1,1]
    const float* bd   = (const float*)d_in[8];   // [1]
    float* out = (float*)d_out;                  // [N,1]

    // workspace (~39.3 MB):
    //   bcur[1024] row_ptr[N_PAD] cnt[N_PAD] col[NBUCKET*BCAP] (9.6MB)
    //   tmp uint[NBUCKET*BCAP] (9.6MB) | y bf16[N,64] (12.8MB) | z2 bf16[N,32] (6.4MB)
    int* bcur    = (int*)d_ws;
    int* row_ptr = bcur + 1024;
    int* cnt     = row_ptr + N_PAD;
    int* col     = cnt + N_PAD;
    unsigned int* tmp  = (unsigned int*)(col + (size_t)NBUCKET * BCAP);
    unsigned short* y  = (unsigned short*)(tmp + (size_t)NBUCKET * BCAP);
    unsigned short* z2 = y + (size_t)N_NODES * 64;   // separate: gather_gemv reads y, writes z2

    hipMemsetAsync((void*)bcur, 0, 1024 * sizeof(int), stream);

    // bucketed CSR build (packed 4B records: src<<7 | dst_local)
    bucket_scatter_lds<<<(N_EDGES + EPB - 1) / EPB, 256, 0, stream>>>(
        esrc, edst, bcur, tmp, N_EDGES);
    bucket_to_csr<<<NBUCKET, 256, 0, stream>>>(tmp, bcur, row_ptr, cnt, col, N_NODES);

    // y = x @ W1 (bf16 row-major)
    gemm_n64<<<(N_NODES + 63) / 64, 256, 0, stream>>>((const float4*)x, W1, y, N_NODES);
    // z2 = relu(mean_agg(y) + b1) @ W2  (fused; h never materialized)
    gather_gemv<<<(N_NODES + 3) / 4, 256, 0, stream>>>(
        (const uint4*)y, row_ptr, col, cnt, b1, W2, z2, N_NODES);
    // out = sigmoid(mean(relu(mean_agg(z2) + b2)) * Wd + bd)
    gather_final32<<<(N_NODES + 3) / 4, 256, 0, stream>>>(
        (const uint4*)z2, row_ptr, col, cnt, b2, Wd, bd, out, N_NODES);
}